// Round 1
// baseline (27.047 us; speedup 1.0000x reference)
//
#include <hip/hip_runtime.h>
#include <hip/hip_bf16.h>
#include <math.h>

// Problem constants (match reference)
#define V1N   225
#define V2N   224
#define RANK  64
#define DDIM  32          // D1 == D2 == 32
#define ROWE  (RANK*DDIM) // 2048 elements per table row
#define NTOK  16384       // B*L = 4*4096

typedef __bf16  bf16x8 __attribute__((ext_vector_type(8)));
typedef float  f32x16 __attribute__((ext_vector_type(16)));

// ---------------------------------------------------------------------------
// Prep: dequantize int8 cores into bf16 tables in d_ws.
// Layout per row v: [s(4)][d(32)][rr(16)]  where r = s*16 + rr.
// This makes each MFMA fragment load a single contiguous 16B (8 x bf16).
// core1 gets scale*(q-zp)*cos(phase[r]); core2 gets scale*(q-zp).
// ---------------------------------------------------------------------------
__global__ __launch_bounds__(256) void prep_tables(
    const int* __restrict__ c1q, const int* __restrict__ c2q,
    const float* __restrict__ s1p, const float* __restrict__ z1p,
    const float* __restrict__ s2p, const float* __restrict__ z2p,
    const float* __restrict__ phase,
    __bf16* __restrict__ t1, __bf16* __restrict__ t2)
{
    int v = blockIdx.x;
    const int* src;
    __bf16* dst;
    float sc, zp;
    bool is1 = (v < V1N);
    if (is1) { src = c1q + v * ROWE;          dst = t1 + v * ROWE;          sc = *s1p; zp = *z1p; }
    else     { int u = v - V1N; src = c2q + u * ROWE; dst = t2 + u * ROWE;  sc = *s2p; zp = *z2p; }

    for (int e = threadIdx.x; e < ROWE; e += 256) {
        int r = e >> 5;      // source layout [r][d]
        int d = e & 31;
        float val = ((float)src[e] - zp) * sc;
        if (is1) val *= cosf(phase[r]);
        // dest [s][d][rr], s = r>>4, rr = r&15
        dst[((r >> 4) * 32 + d) * 16 + (r & 15)] = (__bf16)val;
    }
}

// ---------------------------------------------------------------------------
// Main: one wave per token. 4x mfma_f32_32x32x16_bf16 over rank=64.
// Fragment r-mapping: lane = g*32 + m (m = d-index), reads rr = g*8 + j.
// Same bijection for A and B -> contraction over r is correct regardless of
// the HW's internal A/B k-order (symmetric contraction).
// C/D layout (HW-verified): col = lane&31, row = (reg&3) + 8*(reg>>2) + 4*g.
// ---------------------------------------------------------------------------
__global__ __launch_bounds__(256) void tt_main(
    const int* __restrict__ ids,
    const __bf16* __restrict__ t1, const __bf16* __restrict__ t2,
    float* __restrict__ out, int n_tok)
{
    int wave = (blockIdx.x << 2) + (threadIdx.x >> 6);
    if (wave >= n_tok) return;
    int lane = threadIdx.x & 63;
    int m = lane & 31;
    int g = lane >> 5;

    unsigned id = (unsigned)ids[wave];
    unsigned i1 = id / 224u; if (i1 > (unsigned)(V1N - 1)) i1 = V1N - 1;
    unsigned i2 = id % 224u;

    const __bf16* a_base = t1 + (size_t)i1 * ROWE + m * 16 + g * 8;
    const __bf16* b_base = t2 + (size_t)i2 * ROWE + m * 16 + g * 8;

    f32x16 acc;
    #pragma unroll
    for (int i = 0; i < 16; ++i) acc[i] = 0.0f;

    #pragma unroll
    for (int s = 0; s < 4; ++s) {
        bf16x8 a = *reinterpret_cast<const bf16x8*>(a_base + s * 512);
        bf16x8 b = *reinterpret_cast<const bf16x8*>(b_base + s * 512);
        acc = __builtin_amdgcn_mfma_f32_32x32x16_bf16(a, b, acc, 0, 0, 0);
    }

    float* o = out + (size_t)wave * 1024 + g * 128 + m;
    #pragma unroll
    for (int reg = 0; reg < 16; ++reg) {
        int row = (reg & 3) + 8 * (reg >> 2);
        o[row * 32] = acc[reg];
    }
}

// ---------------------------------------------------------------------------
// Fallback (if d_ws is too small): fused on-the-fly dequant + MFMA.
// ---------------------------------------------------------------------------
__global__ __launch_bounds__(256) void tt_fused(
    const int* __restrict__ ids,
    const int* __restrict__ c1q, const int* __restrict__ c2q,
    const float* __restrict__ s1p, const float* __restrict__ z1p,
    const float* __restrict__ s2p, const float* __restrict__ z2p,
    const float* __restrict__ phase,
    float* __restrict__ out, int n_tok)
{
    __shared__ float cosv[RANK];
    if (threadIdx.x < RANK) cosv[threadIdx.x] = cosf(phase[threadIdx.x]);
    __syncthreads();

    int wave = (blockIdx.x << 2) + (threadIdx.x >> 6);
    if (wave >= n_tok) return;
    int lane = threadIdx.x & 63;
    int m = lane & 31;
    int g = lane >> 5;

    float s1 = *s1p, z1 = *z1p, s2 = *s2p, z2 = *z2p;

    unsigned id = (unsigned)ids[wave];
    unsigned i1 = id / 224u; if (i1 > (unsigned)(V1N - 1)) i1 = V1N - 1;
    unsigned i2 = id % 224u;

    const int* a_src = c1q + (size_t)i1 * ROWE + m;   // [r][d] stride 32
    const int* b_src = c2q + (size_t)i2 * ROWE + m;

    f32x16 acc;
    #pragma unroll
    for (int i = 0; i < 16; ++i) acc[i] = 0.0f;

    #pragma unroll
    for (int s = 0; s < 4; ++s) {
        bf16x8 a, b;
        #pragma unroll
        for (int j = 0; j < 8; ++j) {
            int r = s * 16 + g * 8 + j;
            a[j] = (__bf16)((((float)a_src[r * 32]) - z1) * s1 * cosv[r]);
            b[j] = (__bf16)((((float)b_src[r * 32]) - z2) * s2);
        }
        acc = __builtin_amdgcn_mfma_f32_32x32x16_bf16(a, b, acc, 0, 0, 0);
    }

    float* o = out + (size_t)wave * 1024 + g * 128 + m;
    #pragma unroll
    for (int reg = 0; reg < 16; ++reg) {
        int row = (reg & 3) + 8 * (reg >> 2);
        o[row * 32] = acc[reg];
    }
}

extern "C" void kernel_launch(void* const* d_in, const int* in_sizes, int n_in,
                              void* d_out, int out_size, void* d_ws, size_t ws_size,
                              hipStream_t stream) {
    const int*   ids = (const int*)d_in[0];
    const int*   c1q = (const int*)d_in[1];   // int8 values delivered as int32
    const float* s1  = (const float*)d_in[2];
    const float* z1  = (const float*)d_in[3];
    const int*   c2q = (const int*)d_in[4];
    const float* s2  = (const float*)d_in[5];
    const float* z2  = (const float*)d_in[6];
    const float* ph  = (const float*)d_in[7];
    float* out = (float*)d_out;

    int n_tok = in_sizes[0];                  // 16384
    int grid  = (n_tok + 3) / 4;              // 4 waves (tokens) per block

    size_t need = (size_t)(V1N + V2N) * ROWE * sizeof(__bf16);  // ~1.84 MB
    if (ws_size >= need) {
        __bf16* t1 = (__bf16*)d_ws;
        __bf16* t2 = t1 + (size_t)V1N * ROWE;
        prep_tables<<<V1N + V2N, 256, 0, stream>>>(c1q, c2q, s1, z1, s2, z2, ph, t1, t2);
        tt_main<<<grid, 256, 0, stream>>>(ids, t1, t2, out, n_tok);
    } else {
        tt_fused<<<grid, 256, 0, stream>>>(ids, c1q, c2q, s1, z1, s2, z2, ph, out, n_tok);
    }
}